// Round 20
// baseline (55.263 us; speedup 1.0000x reference)
//
#include <hip/hip_runtime.h>
#include <hip/hip_bf16.h>
#include <string.h>

// GatedEncoderLayer: B=16, I=2048, J=1024, K=1024, F=32
// out[row,k] = sum_f [ (sum_j x[row,j]*Wy[j,f]) * Wx[row%I,f] ] * Wz[k,f]
constexpr int kI = 2048;
constexpr int kJ = 1024;
constexpr int kK = 1024;
constexpr int kF = 32;
constexpr int kRows = 16 * 2048;        // 32768

typedef __attribute__((ext_vector_type(8))) short short8v;
typedef __attribute__((ext_vector_type(4))) float f32x4;

__device__ inline unsigned short bf16_hi_bits(float v) {
    __hip_bfloat16 h = __float2bfloat16(v);      // RNE on gfx950
    unsigned short s;
    memcpy(&s, &h, 2);
    return s;
}
__device__ inline float bf16_bits_to_f(unsigned short s) {
    unsigned u = (unsigned)s << 16;
    float f;
    memcpy(&f, &u, 4);
    return f;
}
__device__ inline short8v as_s8(uint4 u) {
    union { uint4 a; short8v b; } c;
    c.a = u;
    return c.b;
}
// async global->LDS, 16B per lane; LDS dest = wave-uniform base + lane*16
__device__ inline void gl_lds16(const void* g, void* l) {
    __builtin_amdgcn_global_load_lds(
        (const __attribute__((address_space(1))) void*)g,
        (__attribute__((address_space(3))) void*)l,
        16, 0, 0);
}

// ---------------------------------------------------------------------------
// Merged prepack (one launch): e<8192 -> Wy fragments, e>=8192 -> Wz frags.
// Wy entry e = ks*256 + tf*128 + h*64 + lane: elem s -> j; n-col f.
// Wz entry e' = (nt*2+h)*64 + lane: n = nt*16+(lane&15), f = (lane>>4)*8+s
//   — SAME (lane-group,elem)->f map as phase-2's t-row loader.
// ---------------------------------------------------------------------------
__global__ __launch_bounds__(128)
void ge_prepack_all(const float* __restrict__ Wy, const float* __restrict__ Wz,
                    uint4* __restrict__ wyp, uint4* __restrict__ wzp)
{
    const int eg = blockIdx.x * 128 + threadIdx.x;   // 0..16383
    if (eg < 8192) {
        const int e  = eg;
        const int l  = e & 63;
        const int h  = (e >> 6) & 1;
        const int tf = (e >> 7) & 1;
        const int ks = e >> 8;
        const int f  = (l & 15) + tf * 16;
        const int j0 = ks * 32 + (l >> 4) * 8;
        unsigned d[4];
#pragma unroll
        for (int p = 0; p < 4; ++p) {
            const float v0 = Wy[(size_t)(j0 + 2 * p) * kF + f];
            const float v1 = Wy[(size_t)(j0 + 2 * p + 1) * kF + f];
            unsigned short s0, s1;
            if (h == 0) {
                s0 = bf16_hi_bits(v0);
                s1 = bf16_hi_bits(v1);
            } else {
                s0 = bf16_hi_bits(v0 - bf16_bits_to_f(bf16_hi_bits(v0)));
                s1 = bf16_hi_bits(v1 - bf16_bits_to_f(bf16_hi_bits(v1)));
            }
            d[p] = (unsigned)s0 | ((unsigned)s1 << 16);
        }
        wyp[e] = make_uint4(d[0], d[1], d[2], d[3]);
    } else {
        const int e  = eg - 8192;
        const int l  = e & 63;
        const int h  = (e >> 6) & 1;
        const int nt = e >> 7;                       // 0..63
        const int n  = nt * 16 + (l & 15);
        const int f0 = (l >> 4) * 8;
        unsigned d[4];
#pragma unroll
        for (int p = 0; p < 4; ++p) {
            const float v0 = Wz[(size_t)n * kF + f0 + 2 * p];
            const float v1 = Wz[(size_t)n * kF + f0 + 2 * p + 1];
            unsigned short s0, s1;
            if (h == 0) {
                s0 = bf16_hi_bits(v0);
                s1 = bf16_hi_bits(v1);
            } else {
                s0 = bf16_hi_bits(v0 - bf16_bits_to_f(bf16_hi_bits(v0)));
                s1 = bf16_hi_bits(v1 - bf16_bits_to_f(bf16_hi_bits(v1)));
            }
            d[p] = (unsigned)s0 | ((unsigned)s1 << 16);
        }
        wzp[e] = make_uint4(d[0], d[1], d[2], d[3]);
    }
}

// ---------------------------------------------------------------------------
// FUSED all-MFMA kernel (r19 structure + swapped-operand phase-2 stores).
// Phase 1: x@Wy, gl_lds staging, 3-buf rotation, depth-2 counted vmcnt.
// Phase 2: out = t2 @ Wz^T via MFMA, zb double-buffered. NEW (r19 pm):
//   operands SWAPPED — c = mfma(zfrag, tfrag): D m-index = k-quad,
//   n-index = out-row. Lane holds 4 CONSECUTIVE k -> one float4 store
//   (64 stores/thread vs 256 scalar), wave covers 16 rows x 64B contiguous.
//   Legality: both fragments use the same (lane-group,elem)->f map
//   (HW-slot-order invariant, verified empirically r11-19) and the
//   verified D layout with roles exchanged.
// LDS (74 KB, 2 blocks/CU): ph1 xb 48K + bb 24K; ph2 zb 64K + t2 9.2K.
// bf16-split both phases: a*b ~= ah*bh + ah*bl + al*bh (~2^-16 rel).
// ---------------------------------------------------------------------------
__global__ __launch_bounds__(256, 2)
void ge_fused_mfma(const float* __restrict__ x,
                   const float* __restrict__ Wx,
                   const uint4* __restrict__ wyp,
                   const uint4* __restrict__ wzp,
                   float* __restrict__ out)
{
    __shared__ __align__(16) char smem[75776];               // 74 KB
    float4* xb4 = reinterpret_cast<float4*>(smem);           // ph1 [3*1024]
    uint4*  bb4 = reinterpret_cast<uint4*>(smem + 49152);    // ph1 [3*512]
    uint4*  zb  = reinterpret_cast<uint4*>(smem);            // ph2 [2*2048]
    float*  t2  = reinterpret_cast<float*>(smem + 65536);    // ph2 [64*36]

    const int tid  = threadIdx.x;
    const int lane = tid & 63;
    const int wv   = tid >> 6;           // wave 0..3 = m-tile (16 rows)
    const int mrow = lane & 15;
    const int g    = lane >> 4;
    const int rowBase = blockIdx.x * 64;

    f32x4 c0 = {0.f, 0.f, 0.f, 0.f};
    f32x4 c1 = {0.f, 0.f, 0.f, 0.f};

#define STAGE(buf, ti)                                                  \
    {                                                                   \
        _Pragma("unroll")                                               \
        for (int q = 0; q < 4; ++q) {                                   \
            const int srow = wv * 16 + q * 4 + (lane >> 4);             \
            const int sc   = lane & 15;                                 \
            gl_lds16(x + (size_t)(rowBase + srow) * kJ + (ti) * 64      \
                       + 4 * (sc ^ (srow & 7)),                         \
                     &xb4[(buf) * 1024 + (wv * 16 + q * 4) * 16]);      \
        }                                                               \
        _Pragma("unroll")                                               \
        for (int q = 0; q < 2; ++q)                                     \
            gl_lds16(wyp + (size_t)(ti) * 512 + wv * 128 + q * 64 + lane, \
                     &bb4[(buf) * 512 + wv * 128 + q * 64]);            \
    }

    STAGE(0, 0)
    STAGE(1, 1)                          // depth-2 prologue (12 in flight)

#pragma unroll
    for (int ti = 0; ti < 16; ++ti) {
        const int bufR = ti % 3;
        if (ti < 15) {
            asm volatile("s_waitcnt vmcnt(6) lgkmcnt(0)" ::: "memory");
        } else {
            asm volatile("s_waitcnt vmcnt(0) lgkmcnt(0)" ::: "memory");
        }
        asm volatile("s_barrier" ::: "memory");
        __builtin_amdgcn_sched_barrier(0);
        if (ti < 14) { STAGE((ti + 2) % 3, ti + 2) }   // 2 tiles ahead

#pragma unroll
        for (int kk2 = 0; kk2 < 2; ++kk2) {
            const uint4 b0h = bb4[bufR * 512 + kk2 * 256 + lane];
            const uint4 b0l = bb4[bufR * 512 + kk2 * 256 + 64 + lane];
            const uint4 b1h = bb4[bufR * 512 + kk2 * 256 + 128 + lane];
            const uint4 b1l = bb4[bufR * 512 + kk2 * 256 + 192 + lane];

            const int s0 = (kk2 * 8 + g * 2) ^ (mrow & 7);
            const int s1 = (kk2 * 8 + g * 2 + 1) ^ (mrow & 7);
            const float4 xa = xb4[bufR * 1024 + (wv * 16 + mrow) * 16 + s0];
            const float4 xc = xb4[bufR * 1024 + (wv * 16 + mrow) * 16 + s1];
            const float xv[8] = {xa.x, xa.y, xa.z, xa.w,
                                 xc.x, xc.y, xc.z, xc.w};

            short8v ah, al;
#pragma unroll
            for (int e = 0; e < 8; ++e) {
                const unsigned short hb = bf16_hi_bits(xv[e]);
                const float hf = bf16_bits_to_f(hb);
                const unsigned short lb = bf16_hi_bits(xv[e] - hf);
                ah[e] = (short)hb;
                al[e] = (short)lb;
            }

            c0 = __builtin_amdgcn_mfma_f32_16x16x32_bf16(ah, as_s8(b0h), c0, 0, 0, 0);
            c1 = __builtin_amdgcn_mfma_f32_16x16x32_bf16(ah, as_s8(b1h), c1, 0, 0, 0);
            c0 = __builtin_amdgcn_mfma_f32_16x16x32_bf16(ah, as_s8(b0l), c0, 0, 0, 0);
            c1 = __builtin_amdgcn_mfma_f32_16x16x32_bf16(ah, as_s8(b1l), c1, 0, 0, 0);
            c0 = __builtin_amdgcn_mfma_f32_16x16x32_bf16(al, as_s8(b0h), c0, 0, 0, 0);
            c1 = __builtin_amdgcn_mfma_f32_16x16x32_bf16(al, as_s8(b1h), c1, 0, 0, 0);
        }
    }
#undef STAGE

    // --- phase-1 epilogue: gate by Wx, write t2 (aliases upper smem) ---
    __syncthreads();                     // all xb4/bb4 reads done
    {
        const int n = lane & 15;
#pragma unroll
        for (int r = 0; r < 4; ++r) {
            const int rl = wv * 16 + g * 4 + r;
            const int i  = (rowBase + rl) & (kI - 1);
            t2[rl * 36 + n]      = c0[r] * Wx[(size_t)i * kF + n];
            t2[rl * 36 + 16 + n] = c1[r] * Wx[(size_t)i * kF + 16 + n];
        }
    }
    __syncthreads();

    // --- phase 2: out = t2 @ Wz^T, MFMA (swapped operands), dbuf zb ---
#define STAGE_Z(buf, ch)                                                \
    _Pragma("unroll")                                                   \
    for (int q = 0; q < 8; ++q)                                         \
        gl_lds16(wzp + (size_t)(ch) * 2048 + wv * 512 + q * 64 + lane,  \
                 &zb[(buf) * 2048 + wv * 512 + q * 64]);

    STAGE_Z(0, 0)                        // overlaps t-row read/cvt below

    short8v th, tl;
    {
        const float* trow = &t2[(wv * 16 + mrow) * 36 + g * 8];
        const float4 ta = *reinterpret_cast<const float4*>(trow);
        const float4 tb = *reinterpret_cast<const float4*>(trow + 4);
        const float tv[8] = {ta.x, ta.y, ta.z, ta.w, tb.x, tb.y, tb.z, tb.w};
#pragma unroll
        for (int e = 0; e < 8; ++e) {
            const unsigned short hb = bf16_hi_bits(tv[e]);
            const float hf = bf16_bits_to_f(hb);
            const unsigned short lb = bf16_hi_bits(tv[e] - hf);
            th[e] = (short)hb;
            tl[e] = (short)lb;
        }
    }

    // out row owned by this lane (n-index of swapped D): 16 rows x 16 lanes
    const int orow = rowBase + wv * 16 + (lane & 15);
#pragma unroll
    for (int ch = 0; ch < 4; ++ch) {
        if (ch < 3) {
            asm volatile("s_waitcnt vmcnt(8) lgkmcnt(0)" ::: "memory");
        } else {
            asm volatile("s_waitcnt vmcnt(0) lgkmcnt(0)" ::: "memory");
        }
        asm volatile("s_barrier" ::: "memory");
        __builtin_amdgcn_sched_barrier(0);
        if (ch < 3) { STAGE_Z((ch + 1) & 1, ch + 1) }

#pragma unroll
        for (int ntl = 0; ntl < 16; ++ntl) {
            const uint4 bh = zb[(ch & 1) * 2048 + ntl * 128 + lane];
            const uint4 bl = zb[(ch & 1) * 2048 + ntl * 128 + 64 + lane];

            // swapped: A = Wz fragment (m = k), B = t fragment (n = row)
            f32x4 c = {0.f, 0.f, 0.f, 0.f};
            c = __builtin_amdgcn_mfma_f32_16x16x32_bf16(as_s8(bh), th, c, 0, 0, 0);
            c = __builtin_amdgcn_mfma_f32_16x16x32_bf16(as_s8(bl), th, c, 0, 0, 0);
            c = __builtin_amdgcn_mfma_f32_16x16x32_bf16(as_s8(bh), tl, c, 0, 0, 0);

            const int kq = ch * 256 + ntl * 16 + g * 4;   // 4 consecutive k
            float4 o;
            o.x = c[0]; o.y = c[1]; o.z = c[2]; o.w = c[3];
            *reinterpret_cast<float4*>(out + (size_t)orow * kK + kq) = o;
        }
    }
#undef STAGE_Z
}

// ---------------------------------------------------------------------------
// Fallback: round-1 fused VALU kernel (proven correct) if ws too small.
// ---------------------------------------------------------------------------
__global__ __launch_bounds__(256, 2)
void gated_encoder_fused(const float* __restrict__ x,
                         const float* __restrict__ Wx,
                         const float* __restrict__ Wy,
                         const float* __restrict__ Wz,
                         float* __restrict__ out)
{
    __shared__ float t2[64][kF + 4];

    const int tid  = threadIdx.x;
    const int lane = tid & 63;
    const int wv   = tid >> 6;

    const int rloc = wv * 16 + (lane >> 2);
    const int row  = blockIdx.x * 64 + rloc;
    const int fg8  = (lane & 3) * 8;

    const float* __restrict__ xrow = x + (size_t)row * kJ;

    float acc[8];
#pragma unroll
    for (int u = 0; u < 8; ++u) acc[u] = 0.0f;

    for (int j = 0; j < kJ; j += 8) {
        const float4 xv0 = *reinterpret_cast<const float4*>(xrow + j);
        const float4 xv1 = *reinterpret_cast<const float4*>(xrow + j + 4);
        const float xs[8] = {xv0.x, xv0.y, xv0.z, xv0.w,
                             xv1.x, xv1.y, xv1.z, xv1.w};
#pragma unroll
        for (int u = 0; u < 8; ++u) {
            const float* wyp = Wy + (size_t)(j + u) * kF + fg8;
            const float4 w0 = *reinterpret_cast<const float4*>(wyp);
            const float4 w1 = *reinterpret_cast<const float4*>(wyp + 4);
            acc[0] = fmaf(xs[u], w0.x, acc[0]);
            acc[1] = fmaf(xs[u], w0.y, acc[1]);
            acc[2] = fmaf(xs[u], w0.z, acc[2]);
            acc[3] = fmaf(xs[u], w0.w, acc[3]);
            acc[4] = fmaf(xs[u], w1.x, acc[4]);
            acc[5] = fmaf(xs[u], w1.y, acc[5]);
            acc[6] = fmaf(xs[u], w1.z, acc[6]);
            acc[7] = fmaf(xs[u], w1.w, acc[7]);
        }
    }

    const int i = row & (kI - 1);
    const float* wxp = Wx + (size_t)i * kF + fg8;
    const float4 g0 = *reinterpret_cast<const float4*>(wxp);
    const float4 g1 = *reinterpret_cast<const float4*>(wxp + 4);
    float4 r0, r1;
    r0.x = acc[0] * g0.x;  r0.y = acc[1] * g0.y;
    r0.z = acc[2] * g0.z;  r0.w = acc[3] * g0.w;
    r1.x = acc[4] * g1.x;  r1.y = acc[5] * g1.y;
    r1.z = acc[6] * g1.z;  r1.w = acc[7] * g1.w;
    *reinterpret_cast<float4*>(&t2[rloc][fg8])     = r0;
    *reinterpret_cast<float4*>(&t2[rloc][fg8 + 4]) = r1;

    __syncthreads();

    const size_t outBase = (size_t)blockIdx.x * 64 * kK;

#pragma unroll
    for (int pass = 0; pass < 2; ++pass) {
        const int k1 = pass * 512 + tid;
        const int k2 = k1 + 256;
        const float* wz1 = Wz + (size_t)k1 * kF;
        const float* wz2 = Wz + (size_t)k2 * kF;
        float4 z1[8], z2[8];
#pragma unroll
        for (int m = 0; m < 8; ++m) {
            z1[m] = *reinterpret_cast<const float4*>(wz1 + 4 * m);
            z2[m] = *reinterpret_cast<const float4*>(wz2 + 4 * m);
        }
        for (int r = 0; r < 64; ++r) {
            float4 a1 = {0.f, 0.f, 0.f, 0.f};
            float4 a2 = {0.f, 0.f, 0.f, 0.f};
#pragma unroll
            for (int m = 0; m < 8; ++m) {
                const float4 tv = *reinterpret_cast<const float4*>(&t2[r][4 * m]);
                a1.x = fmaf(tv.x, z1[m].x, a1.x);
                a1.y = fmaf(tv.y, z1[m].y, a1.y);
                a1.z = fmaf(tv.z, z1[m].z, a1.z);
                a1.w = fmaf(tv.w, z1[m].w, a1.w);
                a2.x = fmaf(tv.x, z2[m].x, a2.x);
                a2.y = fmaf(tv.y, z2[m].y, a2.y);
                a2.z = fmaf(tv.z, z2[m].z, a2.z);
                a2.w = fmaf(tv.w, z2[m].w, a2.w);
            }
            out[outBase + (size_t)r * kK + k1] = (a1.x + a1.y) + (a1.z + a1.w);
            out[outBase + (size_t)r * kK + k2] = (a2.x + a2.y) + (a2.z + a2.w);
        }
    }
}

extern "C" void kernel_launch(void* const* d_in, const int* in_sizes, int n_in,
                              void* d_out, int out_size, void* d_ws, size_t ws_size,
                              hipStream_t stream) {
    const float* x  = (const float*)d_in[0];   // (B, I, J)
    const float* Wx = (const float*)d_in[1];   // (I, F)
    const float* Wy = (const float*)d_in[2];   // (J, F)
    const float* Wz = (const float*)d_in[3];   // (K, F)
    float* out = (float*)d_out;                // (B, I, K) f32

    const size_t wyBytes = 8192 * sizeof(uint4);   // 128 KiB
    const size_t wzBytes = 8192 * sizeof(uint4);   // 128 KiB

    if (ws_size >= wyBytes + wzBytes && d_ws != nullptr) {
        uint4* wyp = (uint4*)d_ws;
        uint4* wzp = (uint4*)((char*)d_ws + wyBytes);
        ge_prepack_all<<<dim3(128), 128, 0, stream>>>(Wy, Wz, wyp, wzp);
        ge_fused_mfma<<<dim3(kRows / 64), 256, 0, stream>>>(x, Wx, wyp, wzp, out);
    } else {
        gated_encoder_fused<<<dim3(kRows / 64), 256, 0, stream>>>(x, Wx, Wy, Wz, out);
    }
}

// Round 21
// 51.946 us; speedup vs baseline: 1.0639x; 1.0639x over previous
//
#include <hip/hip_runtime.h>
#include <hip/hip_bf16.h>
#include <string.h>

// GatedEncoderLayer: B=16, I=2048, J=1024, K=1024, F=32
// out[row,k] = sum_f [ (sum_j x[row,j]*Wy[j,f]) * Wx[row%I,f] ] * Wz[k,f]
constexpr int kI = 2048;
constexpr int kJ = 1024;
constexpr int kK = 1024;
constexpr int kF = 32;
constexpr int kRows = 16 * 2048;        // 32768

typedef __attribute__((ext_vector_type(8))) short short8v;
typedef __attribute__((ext_vector_type(4))) float f32x4;

__device__ inline unsigned short bf16_hi_bits(float v) {
    __hip_bfloat16 h = __float2bfloat16(v);      // RNE on gfx950
    unsigned short s;
    memcpy(&s, &h, 2);
    return s;
}
__device__ inline float bf16_bits_to_f(unsigned short s) {
    unsigned u = (unsigned)s << 16;
    float f;
    memcpy(&f, &u, 4);
    return f;
}
__device__ inline short8v as_s8(uint4 u) {
    union { uint4 a; short8v b; } c;
    c.a = u;
    return c.b;
}
// async global->LDS, 16B per lane; LDS dest = wave-uniform base + lane*16
__device__ inline void gl_lds16(const void* g, void* l) {
    __builtin_amdgcn_global_load_lds(
        (const __attribute__((address_space(1))) void*)g,
        (__attribute__((address_space(3))) void*)l,
        16, 0, 0);
}

// ---------------------------------------------------------------------------
// Merged prepack (one launch): e<8192 -> Wy fragments, e>=8192 -> Wz frags.
// Wy entry e = ks*256 + tf*128 + h*64 + lane: elem s -> j; n-col f.
// Wz entry e' = (nt*2+h)*64 + lane: n = nt*16+(lane&15), f = (lane>>4)*8+s
//   — SAME (lane-group,elem)->f map as phase-2's A-side t-row loader.
// ---------------------------------------------------------------------------
__global__ __launch_bounds__(128)
void ge_prepack_all(const float* __restrict__ Wy, const float* __restrict__ Wz,
                    uint4* __restrict__ wyp, uint4* __restrict__ wzp)
{
    const int eg = blockIdx.x * 128 + threadIdx.x;   // 0..16383
    if (eg < 8192) {
        const int e  = eg;
        const int l  = e & 63;
        const int h  = (e >> 6) & 1;
        const int tf = (e >> 7) & 1;
        const int ks = e >> 8;
        const int f  = (l & 15) + tf * 16;
        const int j0 = ks * 32 + (l >> 4) * 8;
        unsigned d[4];
#pragma unroll
        for (int p = 0; p < 4; ++p) {
            const float v0 = Wy[(size_t)(j0 + 2 * p) * kF + f];
            const float v1 = Wy[(size_t)(j0 + 2 * p + 1) * kF + f];
            unsigned short s0, s1;
            if (h == 0) {
                s0 = bf16_hi_bits(v0);
                s1 = bf16_hi_bits(v1);
            } else {
                s0 = bf16_hi_bits(v0 - bf16_bits_to_f(bf16_hi_bits(v0)));
                s1 = bf16_hi_bits(v1 - bf16_bits_to_f(bf16_hi_bits(v1)));
            }
            d[p] = (unsigned)s0 | ((unsigned)s1 << 16);
        }
        wyp[e] = make_uint4(d[0], d[1], d[2], d[3]);
    } else {
        const int e  = eg - 8192;
        const int l  = e & 63;
        const int h  = (e >> 6) & 1;
        const int nt = e >> 7;                       // 0..63
        const int n  = nt * 16 + (l & 15);
        const int f0 = (l >> 4) * 8;
        unsigned d[4];
#pragma unroll
        for (int p = 0; p < 4; ++p) {
            const float v0 = Wz[(size_t)n * kF + f0 + 2 * p];
            const float v1 = Wz[(size_t)n * kF + f0 + 2 * p + 1];
            unsigned short s0, s1;
            if (h == 0) {
                s0 = bf16_hi_bits(v0);
                s1 = bf16_hi_bits(v1);
            } else {
                s0 = bf16_hi_bits(v0 - bf16_bits_to_f(bf16_hi_bits(v0)));
                s1 = bf16_hi_bits(v1 - bf16_bits_to_f(bf16_hi_bits(v1)));
            }
            d[p] = (unsigned)s0 | ((unsigned)s1 << 16);
        }
        wzp[e] = make_uint4(d[0], d[1], d[2], d[3]);
    }
}

// ---------------------------------------------------------------------------
// FUSED all-MFMA kernel (r19 = best: 52.0 us; r20's swapped-operand float4
// stores REGRESSED to 55.3 — the scalar-store pattern below is already
// 64B-segment-coalesced (4 segments/instr); vectorizing spread each instr
// over 16 x 4KB-strided rows and hurt. REVERTED.)
// Phase 1: x@Wy, gl_lds staging, 3-buf rotation, DEPTH-2 counted vmcnt:
//   prologue stages tiles 0,1; per tile: wait vmcnt(6) -> s_barrier ->
//   STAGE(t+2) -> compute(t). Race-free: STAGE(t+2) targets buf (t-1)%3
//   whose last reader finished before this tile's barrier.
// Phase 2: out = t2 @ Wz^T via MFMA, zb DOUBLE-buffered (2x32KB):
//   wait vmcnt(8) -> barrier -> STAGE_Z(ch+1) -> compute(ch).
// LDS (74 KB, 2 blocks/CU): ph1 xb 48K + bb 24K; ph2 zb 64K + t2 9.2K.
// bf16-split both phases: a*b ~= ah*bh + ah*bl + al*bh (~2^-16 rel).
// D layout (verified m89 + r11-20 passing): n=lane&15, m=(lane>>4)*4+reg.
// ---------------------------------------------------------------------------
__global__ __launch_bounds__(256, 2)
void ge_fused_mfma(const float* __restrict__ x,
                   const float* __restrict__ Wx,
                   const uint4* __restrict__ wyp,
                   const uint4* __restrict__ wzp,
                   float* __restrict__ out)
{
    __shared__ __align__(16) char smem[75776];               // 74 KB
    float4* xb4 = reinterpret_cast<float4*>(smem);           // ph1 [3*1024]
    uint4*  bb4 = reinterpret_cast<uint4*>(smem + 49152);    // ph1 [3*512]
    uint4*  zb  = reinterpret_cast<uint4*>(smem);            // ph2 [2*2048]
    float*  t2  = reinterpret_cast<float*>(smem + 65536);    // ph2 [64*36]

    const int tid  = threadIdx.x;
    const int lane = tid & 63;
    const int wv   = tid >> 6;           // wave 0..3 = m-tile (16 rows)
    const int mrow = lane & 15;
    const int g    = lane >> 4;
    const int rowBase = blockIdx.x * 64;

    f32x4 c0 = {0.f, 0.f, 0.f, 0.f};
    f32x4 c1 = {0.f, 0.f, 0.f, 0.f};

#define STAGE(buf, ti)                                                  \
    {                                                                   \
        _Pragma("unroll")                                               \
        for (int q = 0; q < 4; ++q) {                                   \
            const int srow = wv * 16 + q * 4 + (lane >> 4);             \
            const int sc   = lane & 15;                                 \
            gl_lds16(x + (size_t)(rowBase + srow) * kJ + (ti) * 64      \
                       + 4 * (sc ^ (srow & 7)),                         \
                     &xb4[(buf) * 1024 + (wv * 16 + q * 4) * 16]);      \
        }                                                               \
        _Pragma("unroll")                                               \
        for (int q = 0; q < 2; ++q)                                     \
            gl_lds16(wyp + (size_t)(ti) * 512 + wv * 128 + q * 64 + lane, \
                     &bb4[(buf) * 512 + wv * 128 + q * 64]);            \
    }

    STAGE(0, 0)
    STAGE(1, 1)                          // depth-2 prologue (12 in flight)

#pragma unroll
    for (int ti = 0; ti < 16; ++ti) {
        const int bufR = ti % 3;
        if (ti < 15) {
            asm volatile("s_waitcnt vmcnt(6) lgkmcnt(0)" ::: "memory");
        } else {
            asm volatile("s_waitcnt vmcnt(0) lgkmcnt(0)" ::: "memory");
        }
        asm volatile("s_barrier" ::: "memory");
        __builtin_amdgcn_sched_barrier(0);
        if (ti < 14) { STAGE((ti + 2) % 3, ti + 2) }   // 2 tiles ahead

#pragma unroll
        for (int kk2 = 0; kk2 < 2; ++kk2) {
            const uint4 b0h = bb4[bufR * 512 + kk2 * 256 + lane];
            const uint4 b0l = bb4[bufR * 512 + kk2 * 256 + 64 + lane];
            const uint4 b1h = bb4[bufR * 512 + kk2 * 256 + 128 + lane];
            const uint4 b1l = bb4[bufR * 512 + kk2 * 256 + 192 + lane];

            const int s0 = (kk2 * 8 + g * 2) ^ (mrow & 7);
            const int s1 = (kk2 * 8 + g * 2 + 1) ^ (mrow & 7);
            const float4 xa = xb4[bufR * 1024 + (wv * 16 + mrow) * 16 + s0];
            const float4 xc = xb4[bufR * 1024 + (wv * 16 + mrow) * 16 + s1];
            const float xv[8] = {xa.x, xa.y, xa.z, xa.w,
                                 xc.x, xc.y, xc.z, xc.w};

            short8v ah, al;
#pragma unroll
            for (int e = 0; e < 8; ++e) {
                const unsigned short hb = bf16_hi_bits(xv[e]);
                const float hf = bf16_bits_to_f(hb);
                const unsigned short lb = bf16_hi_bits(xv[e] - hf);
                ah[e] = (short)hb;
                al[e] = (short)lb;
            }

            c0 = __builtin_amdgcn_mfma_f32_16x16x32_bf16(ah, as_s8(b0h), c0, 0, 0, 0);
            c1 = __builtin_amdgcn_mfma_f32_16x16x32_bf16(ah, as_s8(b1h), c1, 0, 0, 0);
            c0 = __builtin_amdgcn_mfma_f32_16x16x32_bf16(ah, as_s8(b0l), c0, 0, 0, 0);
            c1 = __builtin_amdgcn_mfma_f32_16x16x32_bf16(ah, as_s8(b1l), c1, 0, 0, 0);
            c0 = __builtin_amdgcn_mfma_f32_16x16x32_bf16(al, as_s8(b0h), c0, 0, 0, 0);
            c1 = __builtin_amdgcn_mfma_f32_16x16x32_bf16(al, as_s8(b1h), c1, 0, 0, 0);
        }
    }
#undef STAGE

    // --- phase-1 epilogue: gate by Wx, write t2 (aliases upper smem) ---
    __syncthreads();                     // all xb4/bb4 reads done
    {
        const int n = lane & 15;
#pragma unroll
        for (int r = 0; r < 4; ++r) {
            const int rl = wv * 16 + g * 4 + r;
            const int i  = (rowBase + rl) & (kI - 1);
            t2[rl * 36 + n]      = c0[r] * Wx[(size_t)i * kF + n];
            t2[rl * 36 + 16 + n] = c1[r] * Wx[(size_t)i * kF + 16 + n];
        }
    }
    __syncthreads();

    // --- phase 2: out = t2 @ Wz^T, MFMA, double-buffered zb ---
#define STAGE_Z(buf, ch)                                                \
    _Pragma("unroll")                                                   \
    for (int q = 0; q < 8; ++q)                                         \
        gl_lds16(wzp + (size_t)(ch) * 2048 + wv * 512 + q * 64 + lane,  \
                 &zb[(buf) * 2048 + wv * 512 + q * 64]);

    STAGE_Z(0, 0)                        // overlaps t-row read/cvt below

    short8v th, tl;
    {
        const float* trow = &t2[(wv * 16 + mrow) * 36 + g * 8];
        const float4 ta = *reinterpret_cast<const float4*>(trow);
        const float4 tb = *reinterpret_cast<const float4*>(trow + 4);
        const float tv[8] = {ta.x, ta.y, ta.z, ta.w, tb.x, tb.y, tb.z, tb.w};
#pragma unroll
        for (int e = 0; e < 8; ++e) {
            const unsigned short hb = bf16_hi_bits(tv[e]);
            const float hf = bf16_bits_to_f(hb);
            const unsigned short lb = bf16_hi_bits(tv[e] - hf);
            th[e] = (short)hb;
            tl[e] = (short)lb;
        }
    }

    const int n = lane & 15;
#pragma unroll
    for (int ch = 0; ch < 4; ++ch) {
        if (ch < 3) {
            asm volatile("s_waitcnt vmcnt(8) lgkmcnt(0)" ::: "memory");
        } else {
            asm volatile("s_waitcnt vmcnt(0) lgkmcnt(0)" ::: "memory");
        }
        asm volatile("s_barrier" ::: "memory");
        __builtin_amdgcn_sched_barrier(0);
        if (ch < 3) { STAGE_Z((ch + 1) & 1, ch + 1) }

#pragma unroll
        for (int ntl = 0; ntl < 16; ++ntl) {
            const uint4 bh = zb[(ch & 1) * 2048 + ntl * 128 + lane];
            const uint4 bl = zb[(ch & 1) * 2048 + ntl * 128 + 64 + lane];

            f32x4 c = {0.f, 0.f, 0.f, 0.f};
            c = __builtin_amdgcn_mfma_f32_16x16x32_bf16(th, as_s8(bh), c, 0, 0, 0);
            c = __builtin_amdgcn_mfma_f32_16x16x32_bf16(th, as_s8(bl), c, 0, 0, 0);
            c = __builtin_amdgcn_mfma_f32_16x16x32_bf16(tl, as_s8(bh), c, 0, 0, 0);

            const int k = ch * 256 + ntl * 16 + n;
#pragma unroll
            for (int r = 0; r < 4; ++r) {
                const int row = rowBase + wv * 16 + g * 4 + r;
                out[(size_t)row * kK + k] = c[r];
            }
        }
    }
#undef STAGE_Z
}

// ---------------------------------------------------------------------------
// Fallback: round-1 fused VALU kernel (proven correct) if ws too small.
// ---------------------------------------------------------------------------
__global__ __launch_bounds__(256, 2)
void gated_encoder_fused(const float* __restrict__ x,
                         const float* __restrict__ Wx,
                         const float* __restrict__ Wy,
                         const float* __restrict__ Wz,
                         float* __restrict__ out)
{
    __shared__ float t2[64][kF + 4];

    const int tid  = threadIdx.x;
    const int lane = tid & 63;
    const int wv   = tid >> 6;

    const int rloc = wv * 16 + (lane >> 2);
    const int row  = blockIdx.x * 64 + rloc;
    const int fg8  = (lane & 3) * 8;

    const float* __restrict__ xrow = x + (size_t)row * kJ;

    float acc[8];
#pragma unroll
    for (int u = 0; u < 8; ++u) acc[u] = 0.0f;

    for (int j = 0; j < kJ; j += 8) {
        const float4 xv0 = *reinterpret_cast<const float4*>(xrow + j);
        const float4 xv1 = *reinterpret_cast<const float4*>(xrow + j + 4);
        const float xs[8] = {xv0.x, xv0.y, xv0.z, xv0.w,
                             xv1.x, xv1.y, xv1.z, xv1.w};
#pragma unroll
        for (int u = 0; u < 8; ++u) {
            const float* wyp = Wy + (size_t)(j + u) * kF + fg8;
            const float4 w0 = *reinterpret_cast<const float4*>(wyp);
            const float4 w1 = *reinterpret_cast<const float4*>(wyp + 4);
            acc[0] = fmaf(xs[u], w0.x, acc[0]);
            acc[1] = fmaf(xs[u], w0.y, acc[1]);
            acc[2] = fmaf(xs[u], w0.z, acc[2]);
            acc[3] = fmaf(xs[u], w0.w, acc[3]);
            acc[4] = fmaf(xs[u], w1.x, acc[4]);
            acc[5] = fmaf(xs[u], w1.y, acc[5]);
            acc[6] = fmaf(xs[u], w1.z, acc[6]);
            acc[7] = fmaf(xs[u], w1.w, acc[7]);
        }
    }

    const int i = row & (kI - 1);
    const float* wxp = Wx + (size_t)i * kF + fg8;
    const float4 g0 = *reinterpret_cast<const float4*>(wxp);
    const float4 g1 = *reinterpret_cast<const float4*>(wxp + 4);
    float4 r0, r1;
    r0.x = acc[0] * g0.x;  r0.y = acc[1] * g0.y;
    r0.z = acc[2] * g0.z;  r0.w = acc[3] * g0.w;
    r1.x = acc[4] * g1.x;  r1.y = acc[5] * g1.y;
    r1.z = acc[6] * g1.z;  r1.w = acc[7] * g1.w;
    *reinterpret_cast<float4*>(&t2[rloc][fg8])     = r0;
    *reinterpret_cast<float4*>(&t2[rloc][fg8 + 4]) = r1;

    __syncthreads();

    const size_t outBase = (size_t)blockIdx.x * 64 * kK;

#pragma unroll
    for (int pass = 0; pass < 2; ++pass) {
        const int k1 = pass * 512 + tid;
        const int k2 = k1 + 256;
        const float* wz1 = Wz + (size_t)k1 * kF;
        const float* wz2 = Wz + (size_t)k2 * kF;
        float4 z1[8], z2[8];
#pragma unroll
        for (int m = 0; m < 8; ++m) {
            z1[m] = *reinterpret_cast<const float4*>(wz1 + 4 * m);
            z2[m] = *reinterpret_cast<const float4*>(wz2 + 4 * m);
        }
        for (int r = 0; r < 64; ++r) {
            float4 a1 = {0.f, 0.f, 0.f, 0.f};
            float4 a2 = {0.f, 0.f, 0.f, 0.f};
#pragma unroll
            for (int m = 0; m < 8; ++m) {
                const float4 tv = *reinterpret_cast<const float4*>(&t2[r][4 * m]);
                a1.x = fmaf(tv.x, z1[m].x, a1.x);
                a1.y = fmaf(tv.y, z1[m].y, a1.y);
                a1.z = fmaf(tv.z, z1[m].z, a1.z);
                a1.w = fmaf(tv.w, z1[m].w, a1.w);
                a2.x = fmaf(tv.x, z2[m].x, a2.x);
                a2.y = fmaf(tv.y, z2[m].y, a2.y);
                a2.z = fmaf(tv.z, z2[m].z, a2.z);
                a2.w = fmaf(tv.w, z2[m].w, a2.w);
            }
            out[outBase + (size_t)r * kK + k1] = (a1.x + a1.y) + (a1.z + a1.w);
            out[outBase + (size_t)r * kK + k2] = (a2.x + a2.y) + (a2.z + a2.w);
        }
    }
}

extern "C" void kernel_launch(void* const* d_in, const int* in_sizes, int n_in,
                              void* d_out, int out_size, void* d_ws, size_t ws_size,
                              hipStream_t stream) {
    const float* x  = (const float*)d_in[0];   // (B, I, J)
    const float* Wx = (const float*)d_in[1];   // (I, F)
    const float* Wy = (const float*)d_in[2];   // (J, F)
    const float* Wz = (const float*)d_in[3];   // (K, F)
    float* out = (float*)d_out;                // (B, I, K) f32

    const size_t wyBytes = 8192 * sizeof(uint4);   // 128 KiB
    const size_t wzBytes = 8192 * sizeof(uint4);   // 128 KiB

    if (ws_size >= wyBytes + wzBytes && d_ws != nullptr) {
        uint4* wyp = (uint4*)d_ws;
        uint4* wzp = (uint4*)((char*)d_ws + wyBytes);
        ge_prepack_all<<<dim3(128), 128, 0, stream>>>(Wy, Wz, wyp, wzp);
        ge_fused_mfma<<<dim3(kRows / 64), 256, 0, stream>>>(x, Wx, wyp, wzp, out);
    } else {
        gated_encoder_fused<<<dim3(kRows / 64), 256, 0, stream>>>(x, Wx, Wy, Wz, out);
    }
}